// Round 9
// baseline (1981.657 us; speedup 1.0000x reference)
//
#include <hip/hip_runtime.h>
#include <stdint.h>

#define TT 300

// ws layout (floats)
#define XW0_OFF 0
#define XW0_SZ  (TT*4*1024)          // x@Wih0.T + biases
#define HQ0_OFF (XW0_OFF + XW0_SZ)
#define HQ0_SZ  (TT*1024*2)          // y0 {h,tag} pairs
#define XQ_OFF  (HQ0_OFF + HQ0_SZ)
#define XQ_SZ   (TT*4096)            // xpart values (flag-synced)
#define FLG_OFF (XQ_OFF + XQ_SZ)
#define FLG_SZ  512                  // per-step flags (ints)
#define Y1_OFF  (FLG_OFF + FLG_SZ)   // y1[299], 1024 floats

typedef _Float16 f16x8 __attribute__((ext_vector_type(8)));
typedef float    f32x4 __attribute__((ext_vector_type(4)));

__device__ __forceinline__ float sigf(float x){ return 1.0f/(1.0f+__expf(-x)); }
__device__ __forceinline__ float tahf(float x){ return 1.0f-2.0f/(__expf(2.0f*x)+1.0f); }

// lgkm-only barrier: LDS producer/consumer sync, vmem stays in flight
#define BAR_LGKM() asm volatile("s_waitcnt lgkmcnt(0)\n\ts_barrier" ::: "memory")
// full-drain barrier (also retires vmem stores -> used before flag publish)
#define BAR_FULL() asm volatile("s_waitcnt vmcnt(0) lgkmcnt(0)\n\ts_barrier" ::: "memory")
// issue a dword load (LLC-coherent) WITHOUT waiting; consume after explicit vmcnt
#define LDNW(dst, ptr) asm volatile("global_load_dword %0, %1, off sc0 sc1" \
                                    : "=v"(dst) : "v"(ptr) : "memory")

// poll two {h,tag} pairs (16B) until both tags match (LLC-direct)
__device__ __forceinline__ uint4 poll2(const float* p, unsigned tg) {
  uint4 q; unsigned it = 0;
  do {
    asm volatile("global_load_dwordx4 %0, %1, off sc0 sc1\n\ts_waitcnt vmcnt(0)"
                 : "=v"(q) : "v"(p) : "memory");
  } while ((q.y != tg || q.w != tg) && ++it < (1u<<20));
  return q;
}
__device__ __forceinline__ void pollflag(const int* p, int tg) {
  int v; unsigned it = 0;
  do {
    asm volatile("global_load_dword %0, %1, off sc0 sc1\n\ts_waitcnt vmcnt(0)"
                 : "=v"(v) : "v"(p) : "memory");
  } while (v != tg && ++it < (1u<<22));
}
// fused {h,tag} 8B agent store (data+flag visible atomically in LLC)
__device__ __forceinline__ void store_pair(float* p, float h, unsigned tag) {
  union { struct { float h; unsigned t; } s; unsigned long long u; } pk;
  pk.s.h = h; pk.s.t = tag;
  __hip_atomic_store((unsigned long long*)p, pk.u,
                     __ATOMIC_RELAXED, __HIP_MEMORY_SCOPE_AGENT);
}
__device__ __forceinline__ void store_f32_llc(float* p, float v) {
  asm volatile("global_store_dword %0, %1, off sc0 sc1" :: "v"(p), "v"(v) : "memory");
}

// ------ embedding gather + layer0 input projection + tag/flag zeroing ------
__global__ void emb_proj_k(const float* __restrict__ enc, const int* __restrict__ inp,
                           const float* __restrict__ Wih0, const float* __restrict__ bih0,
                           const float* __restrict__ bhh0, float* __restrict__ xw0,
                           float* __restrict__ hq0, int* __restrict__ flags)
{
  __shared__ float xl[100];
  const int t = blockIdx.x;
  const int tid = threadIdx.x;
  // zero hq0 tags (first-call safety; replays are deterministic anyway)
  for (size_t i = (size_t)t*256 + tid; i < (size_t)TT*1024; i += (size_t)TT*256)
    store_pair(hq0 + i*2, 0.f, 0u);
  if (t == 0) {
    for (int i = tid; i < FLG_SZ; i += 256)
      __hip_atomic_store(&flags[i], 0, __ATOMIC_RELAXED, __HIP_MEMORY_SCOPE_AGENT);
  }
  if (tid < 100) {
    int q = t*100 + tid;
    int s = q / 1200;
    int rm = q - s*1200;
    int bb = rm / 300;
    int e  = rm - bb*300;
    int tok = inp[bb*25 + s];
    xl[tid] = enc[(long)tok*300 + e];
  }
  __syncthreads();
  for (int rr = 0; rr < 4; ++rr) {
    int row = rr*256 + tid;
    const float* wr = Wih0 + row*25;
    float bias = bih0[row] + bhh0[row];
    float a0 = bias, a1 = bias, a2 = bias, a3 = bias;
#pragma unroll
    for (int i = 0; i < 25; ++i) {
      float w = wr[i];
      a0 += w * xl[i];
      a1 += w * xl[25+i];
      a2 += w * xl[50+i];
      a3 += w * xl[75+i];
    }
    xw0[(t*4+0)*1024 + row] = a0;
    xw0[(t*4+1)*1024 + row] = a1;
    xw0[(t*4+2)*1024 + row] = a2;
    xw0[(t*4+3)*1024 + row] = a3;
  }
}

// ------------- persistent scan: 3 WGs x 1024 thr, recurrence-in-WG ---------
// WG0: layer0 (Whh0, K=256). Recurrence internal (LDS). Publishes y0 pairs.
// WG1: xpart = Wih1*y0[t] + bih1 + bhh1 (K=256). Consumes y0 stream (poll,
//      pipelined offset), publishes xq values + per-step flag after drain.
// WG2: layer1 h-part (Whh1, K=256) + gates. Recurrence internal; consumes
//      xq stream (flag-synced, loads issued pre-B1, consumed post-B2).
// All WGs: identical MFMA core (512 x 16x16x32 f16 per step), weights
// resident in VGPRs (128/thread), 2 lgkm-only barriers per step.
__global__ __launch_bounds__(1024, 1) void scan_k(
    const float* __restrict__ Whh0, const float* __restrict__ Wih1,
    const float* __restrict__ Whh1, const float* __restrict__ bih1,
    const float* __restrict__ bhh1, const float* __restrict__ h0in,
    const float* __restrict__ c0in, const float* __restrict__ xw0,
    float* __restrict__ hq0, float* __restrict__ xq,
    int* __restrict__ flags, float* __restrict__ y1out,
    float* __restrict__ dout)
{
  const int wid  = blockIdx.x;        // 0=L0, 1=xpart, 2=L1-h
  const int tid  = threadIdx.x;
  const int lane = tid & 63;
  const int wv   = tid >> 6;          // wave 0..15
  const int ln15 = lane & 15;
  const int kg   = lane >> 4;

  __shared__ _Float16 hb[16][264];    // B operand [b(16)][k(256)+pad]
  __shared__ float    gl[1024*5 + 4]; // MFMA out [row][b] stride 5

  // ---- resident fp16 weight fragments: 4 tiles x 8 ksteps = 128 VGPR ----
  const float* Wsrc = (wid == 0) ? Whh0 : (wid == 1) ? Wih1 : Whh1;
  f16x8 wf[32];
#pragma unroll
  for (int q = 0; q < 4; ++q) {
    int r = (wv*4 + q)*16 + ln15;     // gate row 0..1023
    const float* wr = Wsrc + (size_t)r*256;
#pragma unroll
    for (int kt = 0; kt < 8; ++kt) {
      f16x8 f;
#pragma unroll
      for (int jj = 0; jj < 8; ++jj) f[jj] = (_Float16)wr[kt*32 + kg*8 + jj];
      wf[q*8 + kt] = f;
    }
  }

  // ---- per-thread gate state: (unit ul, batch b) ----
  const int ul = tid >> 2, b = tid & 3;
  float cpr = 0.f, bs0=0.f, bs1=0.f, bs2=0.f, bs3=0.f;
  if (wid == 0) cpr = c0in[b*256 + ul];
  if (wid == 2) cpr = c0in[1024 + b*256 + ul];
  if (wid == 1) {
    bs0 = bih1[0*256+ul] + bhh1[0*256+ul];
    bs1 = bih1[1*256+ul] + bhh1[1*256+ul];
    bs2 = bih1[2*256+ul] + bhh1[2*256+ul];
    bs3 = bih1[3*256+ul] + bhh1[3*256+ul];
  }

  // zero unused B cols 4..15; stage t=0 own-recurrence inputs
  for (int i = tid; i < 12*264; i += 1024) hb[4 + i/264][i%264] = (_Float16)0.f;
  if (wid != 1 && tid < 512) {
    int u = tid >> 1, b0 = (tid & 1)*2;
    int off = (wid == 2) ? 1024 : 0;
    hb[b0+0][u] = (_Float16)h0in[off + (b0+0)*256 + u];
    hb[b0+1][u] = (_Float16)h0in[off + (b0+1)*256 + u];
  }
  __syncthreads();

  for (int t = 0; t < TT; ++t) {
    // ---- role-specific pre-B1 phase ----
    float xwa=0.f, xwb=0.f, xwc=0.f, xwd=0.f;   // WG0
    uint  x0=0, x1=0, x2=0, x3=0;               // WG2
    if (wid == 0) {
      const float* xp = xw0 + (size_t)(t*4 + b)*1024 + ul;  // plain cached;
      xwa = xp[0]; xwb = xp[256]; xwc = xp[512]; xwd = xp[768]; // used post-B2
    } else if (wid == 1) {
      if (tid < 512) {                           // stage y0[t] (poll stream)
        const float* pp = hq0 + ((size_t)t*1024 + (size_t)tid*2)*2;
        uint4 q = poll2(pp, (unsigned)(t+1));
        int u = tid >> 1, b0 = (tid & 1)*2;
        hb[b0+0][u] = (_Float16)__uint_as_float(q.x);
        hb[b0+1][u] = (_Float16)__uint_as_float(q.z);
      }
    } else {
      pollflag(&flags[t], t+1);                  // xpart[t] ready in LLC
      const float* xb = xq + (size_t)t*4096 + tid;
      LDNW(x0, xb); LDNW(x1, xb+1024); LDNW(x2, xb+2048); LDNW(x3, xb+3072);
    }

    // ---- B1: staging/gate-writes visible; vmem stays in flight (WG0/2) ----
    if (wid == 1) {
      BAR_FULL();                                // also retires xq stores(t-1)
      if (tid == 0 && t > 0)
        __hip_atomic_store(&flags[t-1], t, __ATOMIC_RELAXED, __HIP_MEMORY_SCOPE_AGENT);
    } else {
      BAR_LGKM();
    }

    // ---- MFMA: 32 x 16x16x32 f16 per wave, weights resident ----
    f32x4 acc[4];
#pragma unroll
    for (int q = 0; q < 4; ++q) acc[q] = (f32x4){0.f,0.f,0.f,0.f};
#pragma unroll
    for (int kt = 0; kt < 8; ++kt) {
      f16x8 bfr = *(const f16x8*)&hb[ln15][kt*32 + kg*8];
#pragma unroll
      for (int q = 0; q < 4; ++q)
        acc[q] = __builtin_amdgcn_mfma_f32_16x16x32_f16(wf[q*8+kt], bfr, acc[q], 0,0,0);
    }
    if (ln15 < 4) {
#pragma unroll
      for (int q = 0; q < 4; ++q)
#pragma unroll
        for (int i = 0; i < 4; ++i)
          gl[((wv*4+q)*16 + kg*4 + i)*5 + ln15] = acc[q][i];
    }

    // ---- B2: gl ready ----
    BAR_LGKM();

    // ---- role-specific post phase ----
    if (wid == 0) {
      float gi = gl[(0*256+ul)*5 + b] + xwa;
      float gf = gl[(1*256+ul)*5 + b] + xwb;
      float gc = gl[(2*256+ul)*5 + b] + xwc;
      float go = gl[(3*256+ul)*5 + b] + xwd;
      float cn = sigf(gf)*cpr + sigf(gi)*tahf(gc);
      float hn = sigf(go)*tahf(cn);
      cpr = cn;
      hb[b][ul] = (_Float16)hn;                  // internal recurrence (LDS)
      store_pair(hq0 + ((size_t)t*1024 + tid)*2, hn, (unsigned)(t+1));
      if (t == TT-1) {
        dout[400000 + b*256 + ul] = hn;
        dout[400000 + 2048 + b*256 + ul] = cn;
      }
    } else if (wid == 1) {
      float v0 = gl[(0*256+ul)*5 + b] + bs0;
      float v1 = gl[(1*256+ul)*5 + b] + bs1;
      float v2 = gl[(2*256+ul)*5 + b] + bs2;
      float v3 = gl[(3*256+ul)*5 + b] + bs3;
      float* xo = xq + (size_t)t*4096 + tid;
      store_f32_llc(xo,        v0);
      store_f32_llc(xo + 1024, v1);
      store_f32_llc(xo + 2048, v2);
      store_f32_llc(xo + 3072, v3);              // drained at next B1 -> flag
    } else {
      asm volatile("s_waitcnt vmcnt(0)" ::: "memory");  // xq loads landed
      __builtin_amdgcn_sched_barrier(0);
      float gi = gl[(0*256+ul)*5 + b] + __uint_as_float(x0);
      float gf = gl[(1*256+ul)*5 + b] + __uint_as_float(x1);
      float gc = gl[(2*256+ul)*5 + b] + __uint_as_float(x2);
      float go = gl[(3*256+ul)*5 + b] + __uint_as_float(x3);
      float cn = sigf(gf)*cpr + sigf(gi)*tahf(gc);
      float hn = sigf(go)*tahf(cn);
      cpr = cn;
      hb[b][ul] = (_Float16)hn;                  // internal recurrence (LDS)
      if (t == TT-1) {
        store_f32_llc(&y1out[tid], hn);
        dout[400000 + 1024 + b*256 + ul] = hn;
        dout[400000 + 2048 + 1024 + b*256 + ul] = cn;
      }
    }
  }
  if (wid == 1) {                                // final flag after drain
    BAR_FULL();
    if (tid == 0)
      __hip_atomic_store(&flags[TT-1], TT, __ATOMIC_RELAXED, __HIP_MEMORY_SCOPE_AGENT);
  }
}

// ---------------- fc + relu + vocab decode --------------------------------
__global__ void decode_k(const float* __restrict__ y1p, const float* __restrict__ fcW,
                         const float* __restrict__ fcb, const float* __restrict__ decW,
                         const float* __restrict__ decb, float* __restrict__ dout)
{
  __shared__ float y1[1024];   // [j][b]
  __shared__ float o10[40];    // [kk][b]
  const int tid = threadIdx.x;
#pragma unroll
  for (int b = 0; b < 4; ++b)
    y1[tid*4 + b] = y1p[tid*4 + b];
  __syncthreads();
  if (tid < 40) {
    int kk = tid >> 2, b = tid & 3;
    float a = fcb[kk];
    for (int j = 0; j < 256; ++j) a += fcW[kk*256 + j] * y1[j*4 + b];
    o10[kk*4 + b] = fmaxf(a, 0.f);
  }
  __syncthreads();
  int v = blockIdx.x*256 + tid;
  if (v < 100000) {
    const float* dr = decW + (size_t)v*10;
    float bias = decb[v];
    float a0 = bias, a1 = bias, a2 = bias, a3 = bias;
#pragma unroll
    for (int kk = 0; kk < 10; ++kk) {
      float w = dr[kk];
      a0 += w * o10[kk*4+0];
      a1 += w * o10[kk*4+1];
      a2 += w * o10[kk*4+2];
      a3 += w * o10[kk*4+3];
    }
    float4 o; o.x = a0; o.y = a1; o.z = a2; o.w = a3;
    ((float4*)dout)[v] = o;   // decoded.T[v][0..3]
  }
}

extern "C" void kernel_launch(void* const* d_in, const int* in_sizes, int n_in,
                              void* d_out, int out_size, void* d_ws, size_t ws_size,
                              hipStream_t stream)
{
  const float* enc  = (const float*)d_in[0];
  const float* h0in = (const float*)d_in[1];
  const float* c0in = (const float*)d_in[2];
  const float* Wih0 = (const float*)d_in[3];
  const float* Whh0 = (const float*)d_in[4];
  const float* bih0 = (const float*)d_in[5];
  const float* bhh0 = (const float*)d_in[6];
  const float* Wih1 = (const float*)d_in[7];
  const float* Whh1 = (const float*)d_in[8];
  const float* bih1 = (const float*)d_in[9];
  const float* bhh1 = (const float*)d_in[10];
  const float* fcW  = (const float*)d_in[11];
  const float* fcb  = (const float*)d_in[12];
  const float* decW = (const float*)d_in[13];
  const float* decb = (const float*)d_in[14];
  const int*   inp  = (const int*)d_in[15];

  float* ws    = (float*)d_ws;
  float* xw0   = ws + XW0_OFF;
  float* hq0   = ws + HQ0_OFF;
  float* xq    = ws + XQ_OFF;
  int*   flags = (int*)(ws + FLG_OFF);
  float* y1out = ws + Y1_OFF;
  float* dout  = (float*)d_out;

  emb_proj_k<<<TT, 256, 0, stream>>>(enc, inp, Wih0, bih0, bhh0, xw0, hq0, flags);
  scan_k<<<3, 1024, 0, stream>>>(Whh0, Wih1, Whh1, bih1, bhh1,
                                 h0in, c0in, xw0, hq0, xq, flags, y1out, dout);
  decode_k<<<(100000 + 255)/256, 256, 0, stream>>>(y1out, fcW, fcb, decW, decb, dout);
}